// Round 12
// baseline (488.103 us; speedup 1.0000x reference)
//
#include <hip/hip_runtime.h>
#include <hip/hip_fp16.h>

#define NN 32      // nodes
#define FF 64      // GAT out features
#define HH 128     // LSTM hidden
#define G4 512     // 4*H
#define BB 32      // batch
#define TT 512     // time steps
#define ET 128     // 96 edges + 32 self loops
#define NPOS (BB*TT)

__device__ __forceinline__ float frcp(float x) { return __builtin_amdgcn_rcpf(x); }

// ---------------- single worker dispatch: prep (32 blocks) + gatxw (256 blocks) + scan (32) ----
// R22/R23 post-mortem: producer GEMV's 512 broadcast ds_read_b128/thread ~= 20-45us (also
// explains R21's 177us prologue: 4096 b128 x 12cy = 163us), and grid 288 > 256 CUs doubled
// some blocks. R24: grid = 256 = CU count (no doubling possible); block blk produces
// positions blk*64..+63; blk%8==0 blocks also run prep (node blk/8) first and the R20 scan
// (batch blk/8) last. Scanner set {0,8,...,248} lands on distinct CUs under linear,
// XCD-striped, and packed placements. Flags zeroed by a 132B hipMemsetAsync (capturable).
// Sync: prep -> fence -> prep_cnt; all spin prep_cnt==32 -> fence; produce -> fence ->
// flags[b]; scanners spin flags[b]==8 -> fence -> scan. All 256 blocks resident (17.9KB
// LDS, 116 VGPR) => spins cannot deadlock.

#define D2F(HJ, W0, W1, W2, W3) \
  "v_dot2_f32_f16 v216, v" HJ ", v" W0 ", 0\n\t" \
  "v_dot2_f32_f16 v217, v" HJ ", v" W1 ", 0\n\t" \
  "v_dot2_f32_f16 v218, v" HJ ", v" W2 ", 0\n\t" \
  "v_dot2_f32_f16 v219, v" HJ ", v" W3 ", 0\n\t"

#define D2A(HJ, W0, W1, W2, W3) \
  "v_dot2_f32_f16 v216, v" HJ ", v" W0 ", v216\n\t" \
  "v_dot2_f32_f16 v217, v" HJ ", v" W1 ", v217\n\t" \
  "v_dot2_f32_f16 v218, v" HJ ", v" W2 ", v218\n\t" \
  "v_dot2_f32_f16 v219, v" HJ ", v" W3 ", v219\n\t"

#define PHASE(XSLOT, RD, WR) \
  "ds_read_b128 v[32:35], " RD "\n\t" \
  "ds_read_b128 v[36:39], " RD " offset:16\n\t" \
  "ds_read_b128 v[40:43], " RD " offset:32\n\t" \
  "ds_read_b128 v[44:47], " RD " offset:48\n\t" \
  "s_waitcnt lgkmcnt(3)\n\t" \
  D2F("32", "64", "65", "66", "67") \
  D2A("33", "68", "69", "70", "71") \
  D2A("34", "72", "73", "74", "75") \
  D2A("35", "76", "77", "78", "79") \
  "s_waitcnt lgkmcnt(2)\n\t" \
  D2A("36", "80", "81", "82", "83") \
  D2A("37", "84", "85", "86", "87") \
  D2A("38", "88", "89", "90", "91") \
  D2A("39", "92", "93", "94", "95") \
  "s_waitcnt lgkmcnt(1)\n\t" \
  D2A("40", "96", "97", "98", "99") \
  D2A("41", "100", "101", "102", "103") \
  D2A("42", "104", "105", "106", "107") \
  D2A("43", "108", "109", "110", "111") \
  "s_waitcnt lgkmcnt(0)\n\t" \
  D2A("44", "112", "113", "114", "115") \
  D2A("45", "116", "117", "118", "119") \
  D2A("46", "120", "121", "122", "123") \
  D2A("47", "124", "125", "126", "127") \
  "v_add_f32_dpp v216, v216, v216 quad_perm:[1,0,3,2] row_mask:0xf bank_mask:0xf\n\t" \
  "v_add_f32_dpp v217, v217, v217 quad_perm:[1,0,3,2] row_mask:0xf bank_mask:0xf\n\t" \
  "v_add_f32_dpp v218, v218, v218 quad_perm:[1,0,3,2] row_mask:0xf bank_mask:0xf\n\t" \
  "v_add_f32_dpp v219, v219, v219 quad_perm:[1,0,3,2] row_mask:0xf bank_mask:0xf\n\t" \
  "v_add_f32_dpp v216, v216, v216 quad_perm:[2,3,0,1] row_mask:0xf bank_mask:0xf\n\t" \
  "v_add_f32_dpp v217, v217, v217 quad_perm:[2,3,0,1] row_mask:0xf bank_mask:0xf\n\t" \
  "v_add_f32_dpp v218, v218, v218 quad_perm:[2,3,0,1] row_mask:0xf bank_mask:0xf\n\t" \
  "v_add_f32_dpp v219, v219, v219 quad_perm:[2,3,0,1] row_mask:0xf bank_mask:0xf\n\t" \
  "v_cndmask_b32 v208, v216, v217, s[22:23]\n\t" \
  "v_cndmask_b32 v209, v218, v219, s[22:23]\n\t" \
  "v_cndmask_b32 v208, v208, v209, s[24:25]\n\t" \
  "s_waitcnt vmcnt(3)\n\t" \
  "v_mov_b32 v215, " XSLOT "\n\t" \
  "global_load_dword " XSLOT ", v194, %[xwb]\n\t" \
  "v_add_u32 v194, 0x800, v194\n\t" \
  "v_add_f32 v208, v208, v215\n\t" \
  "v_mul_f32 v209, v200, v208\n\t" \
  "v_exp_f32 v209, v209\n\t" \
  "s_nop 0\n\t" \
  "v_add_f32 v209, 1.0, v209\n\t" \
  "v_rcp_f32 v209, v209\n\t" \
  "s_nop 0\n\t" \
  "v_fma_f32 v210, v201, v209, v202\n\t" \
  "s_nop 1\n\t" \
  "v_add_f32_dpp v211, v210, v203 quad_perm:[0,0,0,0] row_mask:0xf bank_mask:0xf\n\t" \
  "v_add_f32_dpp v212, v210, v203 quad_perm:[1,1,1,1] row_mask:0xf bank_mask:0xf\n\t" \
  "v_add_f32_dpp v213, v210, v203 quad_perm:[2,2,2,2] row_mask:0xf bank_mask:0xf\n\t" \
  "v_add_f32_dpp v214, v210, v203 quad_perm:[3,3,3,3] row_mask:0xf bank_mask:0xf\n\t" \
  "v_mul_f32 v211, v211, v213\n\t" \
  "v_fma_f32 v199, v212, v199, v211\n\t" \
  "v_mul_f32 v209, 0x4038aa3b, v199\n\t" \
  "v_exp_f32 v209, v209\n\t" \
  "s_nop 0\n\t" \
  "v_add_f32 v209, 1.0, v209\n\t" \
  "v_rcp_f32 v209, v209\n\t" \
  "s_nop 0\n\t" \
  "v_fma_f32 v209, -2.0, v209, 1.0\n\t" \
  "v_mul_f32 v209, v214, v209\n\t" \
  "v_cvt_f16_f32 v209, v209\n\t" \
  "ds_write_b16 " WR ", v209\n\t" \
  "s_waitcnt lgkmcnt(0)\n\t" \
  "s_barrier\n\t"

__global__ __launch_bounds__(512, 2) void mega_kernel(const float* __restrict__ x_seq,
                                                      const int* __restrict__ ei,
                                                      const float* __restrict__ w_gat,
                                                      const float* __restrict__ att_src,
                                                      const float* __restrict__ att_dst,
                                                      const float* __restrict__ b_gat,
                                                      const float* __restrict__ W_ih,
                                                      const float* __restrict__ W_hh,
                                                      const float* __restrict__ b_ih,
                                                      const float* __restrict__ b_hh,
                                                      const float* __restrict__ W_fc,
                                                      const float* __restrict__ b_fc,
                                                      float* __restrict__ W_eff,
                                                      float* __restrict__ biasp,
                                                      float* __restrict__ Wt,
                                                      float* __restrict__ xw,
                                                      unsigned* __restrict__ flags,
                                                      float* __restrict__ out) {
  __shared__ int srt[ET];
  __shared__ int offs[NN + 1];
  __shared__ int cnt[NN];
  __shared__ float xs[64 * NN];   // 2048: producer round buffer
  __shared__ float sl[64 * NN];   // 2048
  __shared__ float scal_sh[2];
  __shared__ __align__(16) float hlds[160];  // scanner f16 h: hA [0,320)B, hB [320,640)B
  int tid = threadIdx.x;
  int blk = blockIdx.x;
  int b = blk >> 3;
  bool is_scanner = (blk & 7) == 0;

  // ---------- phase 0: prep (scanner blocks only; node n = b) ----------
  if (is_scanner) {
    int n = b, j = tid;
    float accw = 0.f, accb = 0.f;
#pragma unroll 8
    for (int f = 0; f < FF; ++f) {
      float wv = W_ih[(n * FF + f) * G4 + j];
      accw = fmaf(w_gat[f], wv, accw);
      accb = fmaf(b_gat[f], wv, accb);
    }
    W_eff[n * G4 + j] = accw;
    biasp[n * G4 + j] = accb;
    __half* Wt16 = (__half*)Wt;
    int g0 = (n * G4 + j) * 4;
#pragma unroll
    for (int q = 0; q < 4; ++q) {
      int E = g0 + q;
      int tl = E >> 7, idx = E & 127;
      int r = tl >> 2, kq = tl & 3;
      int P = idx >> 3;            // k-pair 0..15
      int g = (idx >> 1) & 3;      // gate
      int e = idx & 1;             // parity within pair
      int k = kq * 32 + 2 * P + e;
      Wt16[E] = __float2half(W_hh[k * G4 + g * 128 + r]);
    }
    __syncthreads();
    __threadfence();               // each thread releases its own prep writes
    __syncthreads();
    if (tid == 0) atomicAdd(&flags[BB], 1u);   // prep counter
  }
  // ---------- all blocks: wait for prep complete ----------
  if (tid == 0) {
    while (atomicAdd(&flags[BB], 0u) < (unsigned)BB) { __builtin_amdgcn_s_sleep(8); }
  }
  __syncthreads();
  __threadfence();                 // acquire: W_eff/biasp/Wt visible

  // ---------- phase 1: producer — gatxw for positions blk*64 .. +63 ----------
  {
    int posbase = blk * 64;
    float wcol[NN];
#pragma unroll
    for (int nn = 0; nn < NN; ++nn) wcol[nn] = W_eff[nn * G4 + tid];
    float bcol = b_ih[tid] + b_hh[tid];
#pragma unroll 8
    for (int nn = 0; nn < NN; ++nn) bcol += biasp[nn * G4 + tid];
    if (tid < NN) cnt[tid] = 0;
    __syncthreads();
    int es = 0, ed = 0, tk = 0;
    if (tid < ET) {
      if (tid < 96) { es = ei[tid]; ed = ei[96 + tid]; }
      else { es = tid - 96; ed = tid - 96; }
      tk = atomicAdd(&cnt[ed], 1);
    }
    __syncthreads();
    if (tid == 0) {
      offs[0] = 0;
      for (int n = 0; n < NN; ++n) offs[n + 1] = offs[n] + cnt[n];
    }
    if (tid == 1) {
      float cs = 0.f, cd = 0.f;
      for (int f = 0; f < FF; ++f) {
        cs = fmaf(w_gat[f], att_src[f], cs);
        cd = fmaf(w_gat[f], att_dst[f], cd);
      }
      scal_sh[0] = cs;
      scal_sh[1] = cd;
    }
    __syncthreads();
    if (tid < ET) srt[offs[ed] + tk] = es;
#pragma unroll
    for (int c = 0; c < 4; ++c)
      xs[c * 512 + tid] = x_seq[(size_t)posbase * NN + c * 512 + tid];  // coalesced
    __syncthreads();
    float cs = scal_sh[0], cd = scal_sh[1];
    int n = tid & 31;
    int e0 = offs[n], e1 = offs[n + 1];
#pragma unroll
    for (int rr = 0; rr < 4; ++rr) {               // softmax: 4 rounds x 16 positions
      int p = rr * 16 + (tid >> 5);
      int base = p * 32;
      float xn = xs[base + n];
      float cdxn = cd * xn;
      float m = -3.0e38f;
      for (int e = e0; e < e1; ++e) {
        float ev = fmaf(cs, xs[base + srt[e]], cdxn);
        ev = ev > 0.f ? ev : 0.2f * ev;             // LeakyReLU(0.2)
        m = fmaxf(m, ev);
      }
      float z = 0.f, sa = 0.f;
      for (int e = e0; e < e1; ++e) {
        float xsv = xs[base + srt[e]];
        float ev = fmaf(cs, xsv, cdxn);
        ev = ev > 0.f ? ev : 0.2f * ev;
        float ex = __expf(ev - m);
        z += ex;
        sa = fmaf(ex, xsv, sa);
      }
      sl[base + n] = sa * frcp(z);
    }
    __syncthreads();
#pragma unroll 4
    for (int pp = 0; pp < 64; ++pp) {              // GEMV: column tid over 32 nodes
      const float4* sp = (const float4*)&sl[pp * 32];
      float a0 = bcol;
#pragma unroll
      for (int q = 0; q < 8; ++q) {
        float4 sv = sp[q];
        a0 = fmaf(sv.x, wcol[4 * q], a0);
        a0 = fmaf(sv.y, wcol[4 * q + 1], a0);
        a0 = fmaf(sv.z, wcol[4 * q + 2], a0);
        a0 = fmaf(sv.w, wcol[4 * q + 3], a0);
      }
      xw[(size_t)(posbase + pp) * G4 + tid] = a0;
    }
    __syncthreads();
    __threadfence();                               // release xw
    __syncthreads();
    if (tid == 0) atomicAdd(&flags[b], 1u);
  }
  if (!is_scanner) return;

  // ---------- phase 2: scanner — R20 LSTM scan for batch b ----------
  if (tid < 160) hlds[tid] = 0.f;                  // f16 zeros
  if (tid == 0) {
    while (atomicAdd(&flags[b], 0u) < 8u) { __builtin_amdgcn_s_sleep(8); }
  }
  __syncthreads();
  __threadfence();                                 // acquire xw
  int r = tid >> 2, kq = tid & 3;
  const float* xwb = xw + (size_t)b * TT * G4;
  unsigned xoff0 = (unsigned)((kq * 128 + r) * 4); // t=0 (xw is f32)
  unsigned wtoff = (unsigned)(tid * 256);          // 128 f16 = 256 B per thread
  unsigned lbase = (unsigned)(uintptr_t)&hlds[0];  // LDS aperture is 4GB-aligned
  unsigned rda = lbase + (unsigned)(kq * 80);      // quarter kq: 32 f16 = 64B (stripe 40 f16)
  unsigned rdb = rda + 320;
  unsigned wra = lbase + (unsigned)(((r >> 5) * 40 + (r & 31)) * 2);  // f16 element
  unsigned wrb = wra + 320;
  float kmulf = (kq == 2) ? __uint_as_float(0x4038aa3bu)   //  2*log2e
                          : __uint_as_float(0xbfb8aa3bu);  // -log2e
  float Af = (kq == 2) ? -2.f : 1.f;
  float Bf = (kq == 2) ? 1.f : 0.f;
  unsigned kqodd = kq & 1, kqhi = kq >> 1;
  __syncthreads();
  asm volatile(
    "v_mov_b32 v194, %[xo]\n\t"
    "v_mov_b32 v195, %[rda]\n\t"
    "v_mov_b32 v196, %[rdb]\n\t"
    "v_mov_b32 v197, %[wra]\n\t"
    "v_mov_b32 v198, %[wrb]\n\t"
    "v_mov_b32 v199, 0\n\t"          // c
    "v_mov_b32 v200, %[km]\n\t"      // kmul
    "v_mov_b32 v201, %[Aa]\n\t"      // A
    "v_mov_b32 v202, %[Bb]\n\t"      // B
    "v_mov_b32 v203, 0\n\t"          // zero (DPP-gather src1)
    "v_cmp_eq_u32 s[22:23], 1, %[kodd]\n\t"
    "v_cmp_eq_u32 s[24:25], 1, %[khi]\n\t"
    // x prefetch ring: t=0..3 -> v224..v227
    "global_load_dword v224, v194, %[xwb]\n\t"
    "v_add_u32 v194, 0x800, v194\n\t"
    "global_load_dword v225, v194, %[xwb]\n\t"
    "v_add_u32 v194, 0x800, v194\n\t"
    "global_load_dword v226, v194, %[xwb]\n\t"
    "v_add_u32 v194, 0x800, v194\n\t"
    "global_load_dword v227, v194, %[xwb]\n\t"
    "v_add_u32 v194, 0x800, v194\n\t"
    // 128 f16 weights -> v64..v127 (16 x dwordx4)
    "global_load_dwordx4 v[64:67], %[wto], %[wtb] offset:0\n\t"
    "global_load_dwordx4 v[68:71], %[wto], %[wtb] offset:16\n\t"
    "global_load_dwordx4 v[72:75], %[wto], %[wtb] offset:32\n\t"
    "global_load_dwordx4 v[76:79], %[wto], %[wtb] offset:48\n\t"
    "global_load_dwordx4 v[80:83], %[wto], %[wtb] offset:64\n\t"
    "global_load_dwordx4 v[84:87], %[wto], %[wtb] offset:80\n\t"
    "global_load_dwordx4 v[88:91], %[wto], %[wtb] offset:96\n\t"
    "global_load_dwordx4 v[92:95], %[wto], %[wtb] offset:112\n\t"
    "global_load_dwordx4 v[96:99], %[wto], %[wtb] offset:128\n\t"
    "global_load_dwordx4 v[100:103], %[wto], %[wtb] offset:144\n\t"
    "global_load_dwordx4 v[104:107], %[wto], %[wtb] offset:160\n\t"
    "global_load_dwordx4 v[108:111], %[wto], %[wtb] offset:176\n\t"
    "global_load_dwordx4 v[112:115], %[wto], %[wtb] offset:192\n\t"
    "global_load_dwordx4 v[116:119], %[wto], %[wtb] offset:208\n\t"
    "global_load_dwordx4 v[120:123], %[wto], %[wtb] offset:224\n\t"
    "global_load_dwordx4 v[124:127], %[wto], %[wtb] offset:240\n\t"
    "s_waitcnt vmcnt(0)\n\t"
    "s_movk_i32 s20, 0x80\n\t"    // 128 iterations x 4 phases = 512 steps
    "L_lstm_%=:\n\t"
    PHASE("v224", "v195", "v198")   // t%4==0: read A, write B
    PHASE("v225", "v196", "v197")   // t%4==1: read B, write A
    PHASE("v226", "v195", "v198")   // t%4==2: read A, write B
    PHASE("v227", "v196", "v197")   // t%4==3: read B, write A
    "s_sub_u32 s20, s20, 1\n\t"
    "s_cmp_lg_u32 s20, 0\n\t"
    "s_cbranch_scc1 L_lstm_%=\n\t"
    "s_waitcnt vmcnt(0) lgkmcnt(0)\n\t"
    :
    : [xwb]"s"(xwb), [wtb]"s"(Wt), [wto]"v"(wtoff), [xo]"v"(xoff0),
      [rda]"v"(rda), [rdb]"v"(rdb), [wra]"v"(wra), [wrb]"v"(wrb),
      [km]"v"(kmulf), [Aa]"v"(Af), [Bb]"v"(Bf),
      [kodd]"v"(kqodd), [khi]"v"(kqhi)
    : "memory", "scc", "s20", "s22", "s23", "s24", "s25",
      "v32","v33","v34","v35","v36","v37","v38","v39",
      "v40","v41","v42","v43","v44","v45","v46","v47",
      "v64","v65","v66","v67","v68","v69","v70","v71",
      "v72","v73","v74","v75","v76","v77","v78","v79",
      "v80","v81","v82","v83","v84","v85","v86","v87",
      "v88","v89","v90","v91","v92","v93","v94","v95",
      "v96","v97","v98","v99","v100","v101","v102","v103",
      "v104","v105","v106","v107","v108","v109","v110","v111",
      "v112","v113","v114","v115","v116","v117","v118","v119",
      "v120","v121","v122","v123","v124","v125","v126","v127",
      "v194","v195","v196","v197","v198","v199",
      "v200","v201","v202","v203","v204","v205","v206","v207",
      "v208","v209","v210","v211","v212","v213","v214","v215",
      "v216","v217","v218","v219",
      "v224","v225","v226","v227");
  __syncthreads();
  // final h (after t=511) is in buffer A as f16: stripe idx (k>>5)*40 + (k&31)
  if (tid < 4) {
    const __half* hf = (const __half*)hlds;
    float acc = b_fc[tid];
#pragma unroll 8
    for (int k = 0; k < HH; ++k)
      acc = fmaf(__half2float(hf[(k >> 5) * 40 + (k & 31)]), W_fc[k * 4 + tid], acc);
    out[b * 4 + tid] = acc;
  }
}

extern "C" void kernel_launch(void* const* d_in, const int* in_sizes, int n_in,
                              void* d_out, int out_size, void* d_ws, size_t ws_size,
                              hipStream_t stream) {
  const float* x_seq   = (const float*)d_in[0];
  const int*   ei      = (const int*)d_in[1];
  const float* w_gat   = (const float*)d_in[2];
  const float* att_src = (const float*)d_in[3];
  const float* att_dst = (const float*)d_in[4];
  const float* b_gat   = (const float*)d_in[5];
  const float* W_ih    = (const float*)d_in[6];
  const float* W_hh    = (const float*)d_in[7];
  const float* b_ih    = (const float*)d_in[8];
  const float* b_hh    = (const float*)d_in[9];
  const float* W_fc    = (const float*)d_in[10];
  const float* b_fc    = (const float*)d_in[11];

  float* ws = (float*)d_ws;
  float* Wt    = ws;                            // 65536 f16 used (region reserved as 65536 f32)
  float* xw    = Wt + 65536;                    // (16384+8)*512 f (pad rows: 4-deep prefetch)
  float* W_eff = xw + (size_t)(NPOS + 8) * G4;  // 32*512
  float* biasp = W_eff + NN * G4;               // 32*512
  unsigned* flags = (unsigned*)(biasp + NN * G4);  // 32 batch flags + 1 prep counter

  hipMemsetAsync(flags, 0, (BB + 1) * sizeof(unsigned), stream);
  mega_kernel<<<BB * 8, G4, 0, stream>>>(x_seq, ei, w_gat, att_src, att_dst, b_gat,
                                         W_ih, W_hh, b_ih, b_hh, W_fc, b_fc,
                                         W_eff, biasp, Wt, xw, flags, (float*)d_out);
}

// Round 13
// 335.977 us; speedup vs baseline: 1.4528x; 1.4528x over previous
//
#include <hip/hip_runtime.h>
#include <hip/hip_fp16.h>

#define NN 32      // nodes
#define FF 64      // GAT out features
#define HH 128     // LSTM hidden
#define G4 512     // 4*H
#define BB 32      // batch
#define TT 512     // time steps
#define ET 128     // 96 edges + 32 self loops
#define NPOS (BB*TT)
#define POSB 32    // positions per gatxw block

__device__ __forceinline__ float frcp(float x) { return __builtin_amdgcn_rcpf(x); }

// ---------------- prep: fold GAT linear + MFMA B-fragment weight transpose ----------------
// R25 layout: lstm thread tid = w*64 + l (wave w 0..7, lane l 0..63). Wave w owns hidden
// units w*16..+15, all 4 gates as 16-col MFMA B tiles. B frag (g,q): lane l holds
// B[k=(l>>4)*8+e][col=l&15] of K-tile q, e=0..7 packed 2/VGPR.
// Wt16[tid*128 + (g*4+q)*8 + e] = f16(W_hh[(q*32 + (l>>4)*8 + e)][g*128 + w*16 + (l&15)])
__global__ __launch_bounds__(512) void prep_kernel(const float* __restrict__ w_gat,
                                                   const float* __restrict__ b_gat,
                                                   const float* __restrict__ W_ih,
                                                   const float* __restrict__ W_hh,
                                                   float* __restrict__ W_eff,
                                                   float* __restrict__ biasp,
                                                   float* __restrict__ Wt) {
  int j = threadIdx.x;
  int n = blockIdx.x;
  float accw = 0.f, accb = 0.f;
#pragma unroll 8
  for (int f = 0; f < FF; ++f) {
    float wv = W_ih[(n * FF + f) * G4 + j];
    accw = fmaf(w_gat[f], wv, accw);
    accb = fmaf(b_gat[f], wv, accb);
  }
  W_eff[n * G4 + j] = accw;
  biasp[n * G4 + j] = accb;
  __half* Wt16 = (__half*)Wt;
  int g0 = (n * G4 + j) * 4;
#pragma unroll
  for (int qq = 0; qq < 4; ++qq) {
    int E = g0 + qq;
    int tl = E >> 7;             // lstm thread 0..511
    int idx = E & 127;
    int frag = idx >> 3;         // 0..15
    int e = idx & 7;
    int g = frag >> 2, q = frag & 3;
    int w = tl >> 6, l = tl & 63;
    int k = q * 32 + ((l >> 4) * 8) + e;
    int col = g * 128 + w * 16 + (l & 15);
    Wt16[E] = __float2half(W_hh[k * G4 + col]);
  }
}

// ---------------- fused GAT + xw: 32 positions per block (R20-verified) ----------------
__global__ __launch_bounds__(256) void gatxw_kernel(const float* __restrict__ x_seq,
                                                    const int* __restrict__ ei,
                                                    const float* __restrict__ w_gat,
                                                    const float* __restrict__ att_src,
                                                    const float* __restrict__ att_dst,
                                                    const float* __restrict__ b_ih,
                                                    const float* __restrict__ b_hh,
                                                    const float* __restrict__ W_eff,
                                                    const float* __restrict__ biasp,
                                                    float* __restrict__ xw) {
  __shared__ int srt[ET];
  __shared__ int offs[NN + 1];
  __shared__ int cnt[NN];
  __shared__ float xs[POSB * NN];   // 1024
  __shared__ float sl[POSB * NN];   // 1024
  __shared__ float scal_sh[2];
  int tid = threadIdx.x;
  int posbase = blockIdx.x * POSB;
  float we0[NN], we1[NN];
#pragma unroll
  for (int nn = 0; nn < NN; ++nn) {
    we0[nn] = W_eff[nn * G4 + tid];
    we1[nn] = W_eff[nn * G4 + 256 + tid];
  }
  float b0 = b_ih[tid] + b_hh[tid];
  float b1 = b_ih[256 + tid] + b_hh[256 + tid];
#pragma unroll 8
  for (int n = 0; n < NN; ++n) {
    b0 += biasp[n * G4 + tid];
    b1 += biasp[n * G4 + 256 + tid];
  }
  if (tid < NN) cnt[tid] = 0;
  __syncthreads();
  int es = 0, ed = 0, tk = 0;
  if (tid < ET) {
    if (tid < 96) { es = ei[tid]; ed = ei[96 + tid]; }
    else { es = tid - 96; ed = tid - 96; }
    tk = atomicAdd(&cnt[ed], 1);
  }
  __syncthreads();
  if (tid == 0) {
    offs[0] = 0;
    for (int n = 0; n < NN; ++n) offs[n + 1] = offs[n] + cnt[n];
  }
  if (tid == 1) {
    float cs = 0.f, cd = 0.f;
    for (int f = 0; f < FF; ++f) {
      cs = fmaf(w_gat[f], att_src[f], cs);
      cd = fmaf(w_gat[f], att_dst[f], cd);
    }
    scal_sh[0] = cs;
    scal_sh[1] = cd;
  }
  __syncthreads();
  if (tid < ET) srt[offs[ed] + tk] = es;
#pragma unroll
  for (int c = 0; c < POSB * NN / 256; ++c)
    xs[c * 256 + tid] = x_seq[posbase * NN + c * 256 + tid];  // coalesced
  __syncthreads();
  float cs = scal_sh[0], cd = scal_sh[1];
  int n = tid & 31;
  int e0 = offs[n], e1 = offs[n + 1];
#pragma unroll
  for (int pb = 0; pb < POSB / 8; ++pb) {
    int p = pb * 8 + (tid >> 5);
    int base = p * 32;
    float xn = xs[base + n];
    float cdxn = cd * xn;
    float m = -3.0e38f;
    for (int e = e0; e < e1; ++e) {
      float ev = fmaf(cs, xs[base + srt[e]], cdxn);
      ev = ev > 0.f ? ev : 0.2f * ev;  // LeakyReLU(0.2)
      m = fmaxf(m, ev);
    }
    float z = 0.f, sa = 0.f;
    for (int e = e0; e < e1; ++e) {
      float xsv = xs[base + srt[e]];
      float ev = fmaf(cs, xsv, cdxn);
      ev = ev > 0.f ? ev : 0.2f * ev;
      float ex = __expf(ev - m);
      z += ex;
      sa = fmaf(ex, xsv, sa);
    }
    sl[base + n] = sa * frcp(z);
  }
  __syncthreads();
#pragma unroll 4
  for (int pp = 0; pp < POSB; ++pp) {
    const float4* sp = (const float4*)&sl[pp * 32];
    float a0 = b0, a1 = b1;
#pragma unroll
    for (int q = 0; q < 8; ++q) {
      float4 sv = sp[q];
      a0 = fmaf(sv.x, we0[4 * q], a0);
      a0 = fmaf(sv.y, we0[4 * q + 1], a0);
      a0 = fmaf(sv.z, we0[4 * q + 2], a0);
      a0 = fmaf(sv.w, we0[4 * q + 3], a0);
      a1 = fmaf(sv.x, we1[4 * q], a1);
      a1 = fmaf(sv.y, we1[4 * q + 1], a1);
      a1 = fmaf(sv.z, we1[4 * q + 2], a1);
      a1 = fmaf(sv.w, we1[4 * q + 3], a1);
    }
    size_t row = (size_t)(posbase + pp) * G4;
    xw[row + tid] = a0;
    xw[row + 256 + tid] = a1;
  }
}

// ---------------- LSTM scan: R25 — MFMA GEMV, lane-local gates ----------------
// R20's 1168cy/step = ~440 issue + ~700 serial (DPP reduce + gate gather + 2 exp chains).
// MFMA reformulation: A = h broadcast to 16 rows (layout forced by arity); B tiles give
// wave w units w*16..+15 x 4 gates; C/D layout (col=lane&15) puts all 4 gate pre-acts
// for unit w*16+(l&15) in reg0 on EVERY lane -> no reduce, no gather, no divergence,
// c lane-local. xw folds into acc init (reg0 re-init each step; regs1-3 accumulate
// identical bounded row-sums, never read). 4-way redundant across l>>4 groups.
//
// Regs: v32-47 A frags | v64-127 B (16 frags x 4) | v194 xaddr | v195/196 rdA/B |
// v197/198 wrA/B | v199 c | v200 -log2e | v201 2log2e | v204-211 act temps |
// v216-231 acc (i,f,g,o) | v240-247 x ring (2 phases x 4 gates)

#define MFMA_Q(AQ, BI, BF, BG, BO) \
  "v_mfma_f32_16x16x32_f16 v[216:219], v[" AQ "], v[" BI "], v[216:219]\n\t" \
  "v_mfma_f32_16x16x32_f16 v[220:223], v[" AQ "], v[" BF "], v[220:223]\n\t" \
  "v_mfma_f32_16x16x32_f16 v[224:227], v[" AQ "], v[" BG "], v[224:227]\n\t" \
  "v_mfma_f32_16x16x32_f16 v[228:231], v[" AQ "], v[" BO "], v[228:231]\n\t"

#define PHASE(X0, X1, X2, X3, RD, WR) \
  "s_waitcnt vmcnt(4)\n\t" \
  "v_mov_b32 v216, " X0 "\n\t" \
  "v_mov_b32 v220, " X1 "\n\t" \
  "v_mov_b32 v224, " X2 "\n\t" \
  "v_mov_b32 v228, " X3 "\n\t" \
  "ds_read_b128 v[32:35], " RD "\n\t" \
  "ds_read_b128 v[36:39], " RD " offset:64\n\t" \
  "ds_read_b128 v[40:43], " RD " offset:128\n\t" \
  "ds_read_b128 v[44:47], " RD " offset:192\n\t" \
  "s_waitcnt lgkmcnt(3)\n\t" \
  MFMA_Q("32:35", "64:67",   "80:83",   "96:99",   "112:115") \
  "s_waitcnt lgkmcnt(2)\n\t" \
  MFMA_Q("36:39", "68:71",   "84:87",   "100:103", "116:119") \
  "s_waitcnt lgkmcnt(1)\n\t" \
  MFMA_Q("40:43", "72:75",   "88:91",   "104:107", "120:123") \
  "s_waitcnt lgkmcnt(0)\n\t" \
  MFMA_Q("44:47", "76:79",   "92:95",   "108:111", "124:127") \
  "global_load_dword " X0 ", v194, %[xwb]\n\t" \
  "global_load_dword " X1 ", v194, %[xwb] offset:512\n\t" \
  "global_load_dword " X2 ", v194, %[xwb] offset:1024\n\t" \
  "global_load_dword " X3 ", v194, %[xwb] offset:1536\n\t" \
  "v_add_u32 v194, 0x800, v194\n\t" \
  "s_nop 7\n\t" \
  "s_nop 7\n\t" \
  "v_mul_f32 v204, v200, v216\n\t" \
  "v_mul_f32 v205, v200, v220\n\t" \
  "v_mul_f32 v206, v201, v224\n\t" \
  "v_mul_f32 v207, v200, v228\n\t" \
  "v_exp_f32 v204, v204\n\t" \
  "v_exp_f32 v205, v205\n\t" \
  "v_exp_f32 v206, v206\n\t" \
  "v_exp_f32 v207, v207\n\t" \
  "v_add_f32 v204, 1.0, v204\n\t" \
  "v_add_f32 v205, 1.0, v205\n\t" \
  "v_add_f32 v206, 1.0, v206\n\t" \
  "v_add_f32 v207, 1.0, v207\n\t" \
  "v_rcp_f32 v204, v204\n\t" \
  "v_rcp_f32 v205, v205\n\t" \
  "v_rcp_f32 v206, v206\n\t" \
  "v_rcp_f32 v207, v207\n\t" \
  "v_fma_f32 v206, -2.0, v206, 1.0\n\t" \
  "v_mul_f32 v210, v204, v206\n\t" \
  "v_fma_f32 v199, v205, v199, v210\n\t" \
  "v_mul_f32 v211, v201, v199\n\t" \
  "v_exp_f32 v211, v211\n\t" \
  "s_nop 0\n\t" \
  "v_add_f32 v211, 1.0, v211\n\t" \
  "v_rcp_f32 v211, v211\n\t" \
  "s_nop 0\n\t" \
  "v_fma_f32 v211, -2.0, v211, 1.0\n\t" \
  "v_mul_f32 v211, v207, v211\n\t" \
  "v_cvt_f16_f32 v211, v211\n\t" \
  "ds_write_b16 " WR ", v211\n\t" \
  "s_waitcnt lgkmcnt(0)\n\t" \
  "s_barrier\n\t"

__global__ __launch_bounds__(512, 2) void lstm_kernel(const float* __restrict__ xw,
                                                      const float* __restrict__ Wt,
                                                      const float* __restrict__ W_fc,
                                                      const float* __restrict__ b_fc,
                                                      float* __restrict__ out) {
  __shared__ __align__(16) float hlds[128];  // f16 h: bufA bytes [0,256), bufB [256,512)
  int b = blockIdx.x, tid = threadIdx.x;
  int w = tid >> 6, l = tid & 63;
  int u = w * 16 + (l & 15);                 // hidden unit (4-way redundant over l>>4)
  if (tid < 128) hlds[tid] = 0.f;
  const float* xwb = xw + (size_t)b * TT * G4;
  unsigned xoff0 = (unsigned)(u * 4);        // xw f32, gate offsets via imm 512B
  unsigned wtoff = (unsigned)(tid * 256);    // 128 f16 = 256 B per thread
  unsigned lbase = (unsigned)(uintptr_t)&hlds[0];  // LDS aperture is 4GB-aligned
  unsigned rda = lbase + (unsigned)((l >> 4) * 16);  // A-frag k-chunk base
  unsigned rdb = rda + 256;
  unsigned wra = lbase + (unsigned)(u * 2);  // f16 element; 4-way same-addr write
  unsigned wrb = wra + 256;
  __syncthreads();
  asm volatile(
    "v_mov_b32 v194, %[xo]\n\t"
    "v_mov_b32 v195, %[rda]\n\t"
    "v_mov_b32 v196, %[rdb]\n\t"
    "v_mov_b32 v197, %[wra]\n\t"
    "v_mov_b32 v198, %[wrb]\n\t"
    "v_mov_b32 v199, 0\n\t"                   // c
    "v_mov_b32 v200, 0xbfb8aa3b\n\t"          // -log2e
    "v_mov_b32 v201, 0x4038aa3b\n\t"          // 2*log2e
    // zero acc regs 1-3 rows (never read; bounded growth) and reg0
    "v_mov_b32 v217, 0\n\t" "v_mov_b32 v218, 0\n\t" "v_mov_b32 v219, 0\n\t"
    "v_mov_b32 v221, 0\n\t" "v_mov_b32 v222, 0\n\t" "v_mov_b32 v223, 0\n\t"
    "v_mov_b32 v225, 0\n\t" "v_mov_b32 v226, 0\n\t" "v_mov_b32 v227, 0\n\t"
    "v_mov_b32 v229, 0\n\t" "v_mov_b32 v230, 0\n\t" "v_mov_b32 v231, 0\n\t"
    // x ring: t=0 -> v240-243, t=1 -> v244-247 (one dword per gate)
    "global_load_dword v240, v194, %[xwb]\n\t"
    "global_load_dword v241, v194, %[xwb] offset:512\n\t"
    "global_load_dword v242, v194, %[xwb] offset:1024\n\t"
    "global_load_dword v243, v194, %[xwb] offset:1536\n\t"
    "v_add_u32 v194, 0x800, v194\n\t"
    "global_load_dword v244, v194, %[xwb]\n\t"
    "global_load_dword v245, v194, %[xwb] offset:512\n\t"
    "global_load_dword v246, v194, %[xwb] offset:1024\n\t"
    "global_load_dword v247, v194, %[xwb] offset:1536\n\t"
    "v_add_u32 v194, 0x800, v194\n\t"
    // 128 f16 B-frag weights -> v64..v127 (16 x dwordx4)
    "global_load_dwordx4 v[64:67], %[wto], %[wtb] offset:0\n\t"
    "global_load_dwordx4 v[68:71], %[wto], %[wtb] offset:16\n\t"
    "global_load_dwordx4 v[72:75], %[wto], %[wtb] offset:32\n\t"
    "global_load_dwordx4 v[76:79], %[wto], %[wtb] offset:48\n\t"
    "global_load_dwordx4 v[80:83], %[wto], %[wtb] offset:64\n\t"
    "global_load_dwordx4 v[84:87], %[wto], %[wtb] offset:80\n\t"
    "global_load_dwordx4 v[88:91], %[wto], %[wtb] offset:96\n\t"
    "global_load_dwordx4 v[92:95], %[wto], %[wtb] offset:112\n\t"
    "global_load_dwordx4 v[96:99], %[wto], %[wtb] offset:128\n\t"
    "global_load_dwordx4 v[100:103], %[wto], %[wtb] offset:144\n\t"
    "global_load_dwordx4 v[104:107], %[wto], %[wtb] offset:160\n\t"
    "global_load_dwordx4 v[108:111], %[wto], %[wtb] offset:176\n\t"
    "global_load_dwordx4 v[112:115], %[wto], %[wtb] offset:192\n\t"
    "global_load_dwordx4 v[116:119], %[wto], %[wtb] offset:208\n\t"
    "global_load_dwordx4 v[120:123], %[wto], %[wtb] offset:224\n\t"
    "global_load_dwordx4 v[124:127], %[wto], %[wtb] offset:240\n\t"
    "s_waitcnt vmcnt(0)\n\t"
    "s_movk_i32 s20, 0x100\n\t"    // 256 iterations x 2 phases = 512 steps
    "L_lstm_%=:\n\t"
    PHASE("v240", "v241", "v242", "v243", "v195", "v198")   // t even: read A, write B
    PHASE("v244", "v245", "v246", "v247", "v196", "v197")   // t odd:  read B, write A
    "s_sub_u32 s20, s20, 1\n\t"
    "s_cmp_lg_u32 s20, 0\n\t"
    "s_cbranch_scc1 L_lstm_%=\n\t"
    "s_waitcnt vmcnt(0) lgkmcnt(0)\n\t"
    :
    : [xwb]"s"(xwb), [wtb]"s"(Wt), [wto]"v"(wtoff), [xo]"v"(xoff0),
      [rda]"v"(rda), [rdb]"v"(rdb), [wra]"v"(wra), [wrb]"v"(wrb)
    : "memory", "scc", "s20",
      "v32","v33","v34","v35","v36","v37","v38","v39",
      "v40","v41","v42","v43","v44","v45","v46","v47",
      "v64","v65","v66","v67","v68","v69","v70","v71",
      "v72","v73","v74","v75","v76","v77","v78","v79",
      "v80","v81","v82","v83","v84","v85","v86","v87",
      "v88","v89","v90","v91","v92","v93","v94","v95",
      "v96","v97","v98","v99","v100","v101","v102","v103",
      "v104","v105","v106","v107","v108","v109","v110","v111",
      "v112","v113","v114","v115","v116","v117","v118","v119",
      "v120","v121","v122","v123","v124","v125","v126","v127",
      "v194","v195","v196","v197","v198","v199","v200","v201",
      "v204","v205","v206","v207","v208","v209","v210","v211",
      "v216","v217","v218","v219","v220","v221","v222","v223",
      "v224","v225","v226","v227","v228","v229","v230","v231",
      "v240","v241","v242","v243","v244","v245","v246","v247");
  __syncthreads();
  // final h (after t=511, odd -> buffer A): f16 linear hlds bytes [0,256)
  if (tid < 4) {
    const __half* hf = (const __half*)hlds;
    float acc = b_fc[tid];
#pragma unroll 8
    for (int k = 0; k < HH; ++k)
      acc = fmaf(__half2float(hf[k]), W_fc[k * 4 + tid], acc);
    out[b * 4 + tid] = acc;
  }
}

extern "C" void kernel_launch(void* const* d_in, const int* in_sizes, int n_in,
                              void* d_out, int out_size, void* d_ws, size_t ws_size,
                              hipStream_t stream) {
  const float* x_seq   = (const float*)d_in[0];
  const int*   ei      = (const int*)d_in[1];
  const float* w_gat   = (const float*)d_in[2];
  const float* att_src = (const float*)d_in[3];
  const float* att_dst = (const float*)d_in[4];
  const float* b_gat   = (const float*)d_in[5];
  const float* W_ih    = (const float*)d_in[6];
  const float* W_hh    = (const float*)d_in[7];
  const float* b_ih    = (const float*)d_in[8];
  const float* b_hh    = (const float*)d_in[9];
  const float* W_fc    = (const float*)d_in[10];
  const float* b_fc    = (const float*)d_in[11];

  float* ws = (float*)d_ws;
  float* Wt    = ws;                            // 65536 f16 used (region reserved as 65536 f32)
  float* xw    = Wt + 65536;                    // (16384+8)*512 f (pad rows: 2-deep prefetch)
  float* W_eff = xw + (size_t)(NPOS + 8) * G4;  // 32*512
  float* biasp = W_eff + NN * G4;               // 32*512

  prep_kernel<<<NN, G4, 0, stream>>>(w_gat, b_gat, W_ih, W_hh, W_eff, biasp, Wt);
  gatxw_kernel<<<NPOS / POSB, 256, 0, stream>>>(x_seq, ei, w_gat, att_src, att_dst,
                                                b_ih, b_hh, W_eff, biasp, xw);
  lstm_kernel<<<BB, G4, 0, stream>>>(xw, Wt, W_fc, b_fc, (float*)d_out);
}